// Round 1
// baseline (50353.864 us; speedup 1.0000x reference)
//
#include <hip/hip_runtime.h>
#include <math.h>

#define DI __device__ __forceinline__

namespace {

constexpr int Bb = 4, Tt = 2048, Dd = 1024, Cc = 16, NCc = 128;
constexpr int DOUTS[6] = {1024, 1024, 1024, 1, 1, 1024};
constexpr int BIGM[4] = {0, 1, 2, 5};

constexpr long SZ_BIG = (long)Dd * Dd + (long)Dd * Dd + 1024 + 1024;          // 2,099,200
constexpr long SZ_SMALL = (long)Dd * Dd + 1024 + 1024 + 1024;                 // 1,051,648
constexpr long MODOFF[6] = {0, SZ_BIG, 2 * SZ_BIG, 3 * SZ_BIG,
                            3 * SZ_BIG + SZ_SMALL, 3 * SZ_BIG + 2 * SZ_SMALL};
constexpr long BSTRIDE = 3 * SZ_BIG + 2 * SZ_SMALL + SZ_BIG;                  // 10,500,096

constexpr long OFF_Z     = 0;
constexpr long OFF_STATE = OFF_Z + (long)Bb * Tt * Dd;
constexpr long OFF_PRE5  = OFF_STATE + 4 * BSTRIDE;
constexpr long OFF_KVQ   = OFF_PRE5 + (long)Bb * 5 * Cc * Dd;
constexpr long OFF_PREV  = OFF_KVQ + (long)Bb * 3 * Cc * Dd;
constexpr long OFF_PREK  = OFF_PREV + (long)Bb * 6 * Cc * Dd;
constexpr long OFF_PREO  = OFF_PREK + (long)Bb * 6 * Cc * Dd;
constexpr long OFF_ERR   = OFF_PREO + (long)Bb * Cc * Dd;
constexpr long OFF_DLP   = OFF_ERR + (long)Bb * 6 * Cc * Dd;
constexpr long OFF_RSSQ  = OFF_DLP + (long)Bb * 6 * Cc * Dd;   // [B][2][16]
constexpr long OFF_EA    = OFF_RSSQ + Bb * 2 * Cc;             // [0..3]=ea, [4..7]=aa
constexpr long OFF_SCALE = OFF_EA + 8;                         // 96
constexpr long OFF_SUMSQ = OFF_SCALE + 96;                     // 96
constexpr long OFF_INWT  = OFF_SUMSQ + 96;
constexpr long OFF_OUTWT = OFF_INWT + (long)Dd * Dd;
constexpr long WS_FLOATS = OFF_OUTWT + (long)Dd * Dd;          // ~54.65M floats (~219 MB)

struct InPtrs { const float* p[31]; };

DI float* stateBase(float* ws, int b, int m) {
  return ws + OFF_STATE + (long)b * BSTRIDE + MODOFF[m];
}
DI int sidx(int b, int m, int p) { return ((b * 6 + m) << 2) + p; }  // p: 0 W1,1 b1,2 W2,3 b2
DI float maxnf(int m, int p) {
  switch (p) {
    case 0: return sqrtf((float)(Dd * DOUTS[m]));
    case 1: return sqrtf((float)DOUTS[m]);
    case 2: return 1024.0f;
    default: return 32.0f;
  }
}
DI float sigm(float x) { return 1.0f / (1.0f + expf(-x)); }
DI float silu(float x) { return x * sigm(x); }

DI void sumsqReduce(float ss, float* slack, float* dst) {
#pragma unroll
  for (int st = 32; st >= 1; st >>= 1) ss += __shfl_xor(ss, st);
  const int tid = threadIdx.x;
  if ((tid & 63) == 0) slack[tid >> 6] = ss;
  __syncthreads();
  if (tid == 0) atomicAdd(dst, slack[0] + slack[1] + slack[2] + slack[3]);
  __syncthreads();
}

// ---------- generic 16xN GEMM core: Y[c][n] = sum_k X[c][k]*A[k][n], A row-major [K=1024][N=1024]
// 256 threads: 4 waves split K (256 each); thread owns columns n0+l and n0+64+l for all 16 rows.
// sm layout: Xs [4][16][68] (4352 floats) | red [4][16][128] (8192 floats) -> 12544 floats total.
template <class XF, class EF>
DI void core16(float* sm, XF&& xf, const float* __restrict__ A, int n0, EF&& ef) {
  float* Xs = sm;
  float* red = sm + 4352;
  const int tid = threadIdx.x, g = tid >> 6, l = tid & 63;
  float acc0[16], acc1[16];
#pragma unroll
  for (int c = 0; c < 16; c++) { acc0[c] = 0.f; acc1[c] = 0.f; }
#pragma unroll 1
  for (int s = 0; s < 4; s++) {
    const int kb = (g << 8) + (s << 6);
    __syncthreads();
    float* xr = Xs + (g * 16) * 68 + l;
#pragma unroll
    for (int c = 0; c < 16; c++) xr[c * 68] = xf(c, kb + l);
    __syncthreads();
    const float* Ap = A + (long)kb * Dd + n0 + l;
#pragma unroll 2
    for (int j = 0; j < 64; j += 4) {
      const float a00 = Ap[(long)(j + 0) * Dd], a01 = Ap[(long)(j + 1) * Dd];
      const float a02 = Ap[(long)(j + 2) * Dd], a03 = Ap[(long)(j + 3) * Dd];
      const float a10 = Ap[(long)(j + 0) * Dd + 64], a11 = Ap[(long)(j + 1) * Dd + 64];
      const float a12 = Ap[(long)(j + 2) * Dd + 64], a13 = Ap[(long)(j + 3) * Dd + 64];
#pragma unroll
      for (int c = 0; c < 16; c++) {
        const float4 xv = *reinterpret_cast<const float4*>(&Xs[(g * 16 + c) * 68 + j]);
        float t0 = acc0[c], t1 = acc1[c];
        t0 = fmaf(xv.x, a00, t0); t0 = fmaf(xv.y, a01, t0);
        t0 = fmaf(xv.z, a02, t0); t0 = fmaf(xv.w, a03, t0);
        t1 = fmaf(xv.x, a10, t1); t1 = fmaf(xv.y, a11, t1);
        t1 = fmaf(xv.z, a12, t1); t1 = fmaf(xv.w, a13, t1);
        acc0[c] = t0; acc1[c] = t1;
      }
    }
  }
  __syncthreads();
#pragma unroll
  for (int c = 0; c < 16; c++) {
    red[(g * 16 + c) * 128 + l] = acc0[c];
    red[(g * 16 + c) * 128 + 64 + l] = acc1[c];
  }
  __syncthreads();
#pragma unroll
  for (int i = 0; i < 8; i++) {
    const int flat = tid * 8 + i, c = flat >> 7, n = flat & 127;
    const float v = red[(0 * 16 + c) * 128 + n] + red[(1 * 16 + c) * 128 + n] +
                    red[(2 * 16 + c) * 128 + n] + red[(3 * 16 + c) * 128 + n];
    ef(c, n0 + n, v);
  }
}

// ---------- dual-X core: two 16xN GEMMs sharing one pass over A.
// sm: Xs [4][16][72] (X1 at +0..31, X2 at +36..67) = 4608 | red 8192 -> 12800 floats.
template <class XF1, class XF2, class EF>
DI void core16d(float* sm, XF1&& xf1, XF2&& xf2, const float* __restrict__ A, int n0, EF&& ef) {
  float* Xs = sm;
  float* red = sm + 4608;
  const int tid = threadIdx.x, g = tid >> 6, l = tid & 63;
  float av0[16], av1[16], ap0[16], ap1[16];
#pragma unroll
  for (int c = 0; c < 16; c++) { av0[c] = 0.f; av1[c] = 0.f; ap0[c] = 0.f; ap1[c] = 0.f; }
#pragma unroll 1
  for (int s = 0; s < 8; s++) {
    const int kb = (g << 8) + (s << 5);
    __syncthreads();
    float* xr = Xs + (g * 16) * 72;
    if (l < 32) {
#pragma unroll
      for (int c = 0; c < 16; c++) xr[c * 72 + l] = xf1(c, kb + l);
    } else {
#pragma unroll
      for (int c = 0; c < 16; c++) xr[c * 72 + 36 + (l - 32)] = xf2(c, kb + l - 32);
    }
    __syncthreads();
    const float* Ap = A + (long)kb * Dd + n0 + l;
#pragma unroll 1
    for (int j = 0; j < 32; j += 4) {
      const float a00 = Ap[(long)(j + 0) * Dd], a01 = Ap[(long)(j + 1) * Dd];
      const float a02 = Ap[(long)(j + 2) * Dd], a03 = Ap[(long)(j + 3) * Dd];
      const float a10 = Ap[(long)(j + 0) * Dd + 64], a11 = Ap[(long)(j + 1) * Dd + 64];
      const float a12 = Ap[(long)(j + 2) * Dd + 64], a13 = Ap[(long)(j + 3) * Dd + 64];
#pragma unroll
      for (int c = 0; c < 16; c++) {
        const float4 x1 = *reinterpret_cast<const float4*>(&Xs[(g * 16 + c) * 72 + j]);
        const float4 x2 = *reinterpret_cast<const float4*>(&Xs[(g * 16 + c) * 72 + 36 + j]);
        float t;
        t = av0[c]; t = fmaf(x1.x, a00, t); t = fmaf(x1.y, a01, t); t = fmaf(x1.z, a02, t); t = fmaf(x1.w, a03, t); av0[c] = t;
        t = av1[c]; t = fmaf(x1.x, a10, t); t = fmaf(x1.y, a11, t); t = fmaf(x1.z, a12, t); t = fmaf(x1.w, a13, t); av1[c] = t;
        t = ap0[c]; t = fmaf(x2.x, a00, t); t = fmaf(x2.y, a01, t); t = fmaf(x2.z, a02, t); t = fmaf(x2.w, a03, t); ap0[c] = t;
        t = ap1[c]; t = fmaf(x2.x, a10, t); t = fmaf(x2.y, a11, t); t = fmaf(x2.z, a12, t); t = fmaf(x2.w, a13, t); ap1[c] = t;
      }
    }
  }
  __syncthreads();
#pragma unroll
  for (int c = 0; c < 16; c++) {
    red[(g * 16 + c) * 128 + l] = av0[c];
    red[(g * 16 + c) * 128 + 64 + l] = av1[c];
  }
  __syncthreads();
  float vv[8];
#pragma unroll
  for (int i = 0; i < 8; i++) {
    const int flat = tid * 8 + i, c = flat >> 7, n = flat & 127;
    vv[i] = red[(0 * 16 + c) * 128 + n] + red[(1 * 16 + c) * 128 + n] +
            red[(2 * 16 + c) * 128 + n] + red[(3 * 16 + c) * 128 + n];
  }
  __syncthreads();
#pragma unroll
  for (int c = 0; c < 16; c++) {
    red[(g * 16 + c) * 128 + l] = ap0[c];
    red[(g * 16 + c) * 128 + 64 + l] = ap1[c];
  }
  __syncthreads();
#pragma unroll
  for (int i = 0; i < 8; i++) {
    const int flat = tid * 8 + i, c = flat >> 7, n = flat & 127;
    const float pp = red[(0 * 16 + c) * 128 + n] + red[(1 * 16 + c) * 128 + n] +
                     red[(2 * 16 + c) * 128 + n] + red[(3 * 16 + c) * 128 + n];
    ef(c, n0 + n, vv[i], pp);
  }
}

// ============================ prologue ============================

__global__ __launch_bounds__(256) void k_p0(float* ws, InPtrs in) {
  const long i = threadIdx.x + (long)blockIdx.x * 256;
  if (i < 96) { ws[OFF_SCALE + i] = 1.f; return; }
  if (i < 192) { ws[OFF_SUMSQ + (i - 96)] = 0.f; return; }
  if (i < 320) { ws[OFF_RSSQ + (i - 192)] = 0.f; return; }
  const long j = i - 320;
  if (j < 24 * 2048) {
    const int bm = (int)(j >> 11), q = (int)(j & 2047);
    const int b = bm / 6, m = bm % 6;
    float* base = stateBase(ws, b, m);
    float* b1 = base + (long)Dd * Dd + (long)Dd * DOUTS[m];
    if (q < 1024) {
      if (q < DOUTS[m]) b1[q] = in.p[2 + 4 * m][q];
    } else {
      b1[1024 + (q - 1024)] = in.p[4 + 4 * m][q - 1024];
    }
    return;
  }
  const long j2 = j - 49152;
  if (j2 < 8192) {
    const int e = (int)(j2 >> 10), b = e >> 1, m = 3 + (e & 1);
    const int h = (int)(j2 & 1023);
    (stateBase(ws, b, m) + (long)Dd * Dd)[h] = in.p[1 + 4 * m][h];
  }
}

// tiled transposes: W2->W2T (x4 batches), big W1->W1T (x4), in_W->in_WT, out_W->out_WT
__global__ __launch_bounds__(256) void k_p1(float* ws, InPtrs in) {
  __shared__ float tile[64][65];
  const int bid = blockIdx.x, ti = bid & 255, j = bid >> 8;
  const int tr = (ti >> 4) << 6, tc = (ti & 15) << 6;
  const float* src; float* dst; int nb;
  if (j < 6) { src = in.p[3 + 4 * j]; dst = ws + OFF_STATE + MODOFF[j]; nb = 4; }
  else if (j < 10) { const int m = BIGM[j - 6]; src = in.p[1 + 4 * m]; dst = ws + OFF_STATE + MODOFF[m] + (long)Dd * Dd; nb = 4; }
  else if (j == 10) { src = in.p[25]; dst = ws + OFF_INWT; nb = 1; }
  else { src = in.p[27]; dst = ws + OFF_OUTWT; nb = 1; }
  const int l = threadIdx.x & 63, wq = threadIdx.x >> 6;
  for (int r = wq; r < 64; r += 4) tile[r][l] = src[(long)(tr + r) * Dd + tc + l];
  __syncthreads();
  for (int r = wq; r < 64; r += 4) {
    const float v = tile[l][r];
    for (int q = 0; q < nb; q++) dst[(long)q * BSTRIDE + (long)(tc + r) * Dd + tr + l] = v;
  }
}

// big GEMM for z = x@in_W^T + in_b and final y = LN@out_W^T + out_b
__global__ __launch_bounds__(256) void k_gemm_big(const float* __restrict__ X,
                                                  const float* __restrict__ A,
                                                  const float* __restrict__ bias,
                                                  float* __restrict__ Y) {
  __shared__ float sm[12544];
  const int bid = blockIdx.x, tile = bid & 7;
  const long rb = bid >> 3;
  const float* Xr = X + rb * 16 * 1024;
  float* Yr = Y + rb * 16 * 1024;
  core16(sm, [&](int c, int k) { return Xr[(long)c * 1024 + k]; }, A, tile * 128,
         [&](int c, int n, float v) { Yr[(long)c * 1024 + n] = v + bias[n]; });
}

// ============================ per-step kernels ============================

__global__ __launch_bounds__(256) void k_s0(float* ws, int t) {
  const int i = threadIdx.x;
  if (i < 96) {
    const float ssv = ws[OFF_SUMSQ + i];
    const int p = i & 3, m = (i >> 2) % 6;
    ws[OFF_SCALE + i] = fminf(maxnf(m, p) / (sqrtf(ssv) + 1e-8f), 1.0f);
    ws[OFF_SUMSQ + i] = 0.f;
  } else if (i < 224) {
    ws[OFF_RSSQ + (i - 96)] = 0.f;
  }
  (void)t;
}

// S1: pre_m = cW2*(z @ W2T) + cb2*b2 for m in {k,v,q,eta,alpha}. grid 160.
__global__ __launch_bounds__(256) void k_s1(float* ws, int t) {
  __shared__ float sm[12544];
  const int bid = blockIdx.x, tile = bid & 7, m = (bid >> 3) % 5, b = bid / 40;
  const float* zc = ws + OFF_Z + ((long)b * Tt + (long)t * Cc) * Dd;
  const float* A = stateBase(ws, b, m);
  const float* scl = ws + OFF_SCALE;
  const float cW2 = scl[sidx(b, m, 2)], cb2 = scl[sidx(b, m, 3)];
  const float* b2 = stateBase(ws, b, m) + (long)Dd * Dd + (long)Dd * DOUTS[m] + 1024;
  float* Y = ws + OFF_PRE5 + ((long)b * 5 + m) * Cc * Dd;
  core16(sm, [&](int c, int k) { return zc[(long)c * Dd + k]; }, A, tile * 128,
         [&](int c, int n, float v) { Y[(long)c * Dd + n] = fmaf(cW2, v, cb2 * b2[n]); });
}

// S2: out_{k,v,q} = cW1*(silu(pre)@W1T) + cb1*b1 + z ; rowsumsq for k,q ; eta/alpha heads -> ea/aa.
__global__ __launch_bounds__(256) void k_s2(float* ws, int t) {
  __shared__ float sm[12544 + 16];
  const int tid = threadIdx.x, bid = blockIdx.x;
  const float* scl = ws + OFF_SCALE;
  if (bid < 96) {
    const int tile = bid & 7, m = (bid >> 3) % 3, b = bid / 24;
    if (tid < 16) sm[12544 + tid] = 0.f;
    const float* pre = ws + OFF_PRE5 + ((long)b * 5 + m) * Cc * Dd;
    const float* A = stateBase(ws, b, m) + (long)Dd * Dd;
    const float* zc = ws + OFF_Z + ((long)b * Tt + (long)t * Cc) * Dd;
    const float cW1 = scl[sidx(b, m, 0)], cb1 = scl[sidx(b, m, 1)];
    const float* b1 = stateBase(ws, b, m) + (long)Dd * Dd + (long)Dd * DOUTS[m];
    float* out = ws + OFF_KVQ + ((long)b * 3 + m) * Cc * Dd;
    const bool sq = (m != 1);
    const int which = (m == 0) ? 0 : 1;
    core16(sm, [&](int c, int k) { return silu(pre[(long)c * Dd + k]); }, A, tile * 128,
           [&](int c, int n, float v) {
             const float val = fmaf(cW1, v, fmaf(cb1, b1[n], zc[(long)c * Dd + n]));
             out[(long)c * Dd + n] = val;
             if (sq) atomicAdd(&sm[12544 + c], val * val);
           });
    __syncthreads();
    if (sq && tid < 16)
      atomicAdd(ws + OFF_RSSQ + ((long)b * 2 + which) * Cc + tid, sm[12544 + tid]);
  } else {
    const int e = bid - 96, b = e >> 1, m = 3 + (e & 1);
    const float* pre = ws + OFF_PRE5 + ((long)b * 5 + m) * Cc * Dd;
    const float* w1 = stateBase(ws, b, m) + (long)Dd * Dd;
    float av[16];
#pragma unroll
    for (int c = 0; c < 16; c++) av[c] = 0.f;
    for (int jj = 0; jj < 4; jj++) {
      const int h = tid + 256 * jj;
      const float w = w1[h];
#pragma unroll
      for (int c = 0; c < 16; c++) av[c] = fmaf(silu(pre[(long)c * Dd + h]), w, av[c]);
    }
#pragma unroll
    for (int st = 1; st < 64; st <<= 1)
#pragma unroll
      for (int c = 0; c < 16; c++) av[c] += __shfl_xor(av[c], st);
    if ((tid & 63) == 0) {
      const int w4 = tid >> 6;
#pragma unroll
      for (int c = 0; c < 16; c++) sm[w4 * 16 + c] = av[c];
    }
    __syncthreads();
    if (tid == 0) {
      const float cW1 = scl[sidx(b, m, 0)], cb1 = scl[sidx(b, m, 1)];
      const float b10 = (stateBase(ws, b, m) + (long)Dd * Dd + 1024)[0];
      float s = 0.f;
      for (int c = 0; c < 16; c++) {
        const float tot = sm[c] + sm[16 + c] + sm[32 + c] + sm[48 + c];
        s += sigm(fmaf(cW1, tot, cb1 * b10));
      }
      ws[OFF_EA + ((m == 3) ? 0 : 4) + b] = s * 0.0625f;
    }
  }
}

// S3: pre_v[m] (X=v), pre_k[m] (X=k_normalized) for all 6 modules, pre_o (X=q_normalized, memory). grid 416.
__global__ __launch_bounds__(256) void k_s3(float* ws) {
  __shared__ float sm[12544 + 16];
  const int tid = threadIdx.x, bid = blockIdx.x;
  const int tile = bid % 8, job = (bid / 8) % 13, b = bid / 104;
  const float* scl = ws + OFF_SCALE;
  if (job < 12) {
    const int m = (job < 6) ? job : job - 6;
    const bool useK = (job >= 6);
    const float* X = ws + OFF_KVQ + ((long)b * 3 + (useK ? 0 : 1)) * Cc * Dd;
    float* Y = ws + (useK ? OFF_PREK : OFF_PREV) + ((long)b * 6 + m) * Cc * Dd;
    if (useK && tid < 16) {
      const float ssv = ws[OFF_RSSQ + (long)b * 2 * Cc + tid];
      sm[12544 + tid] = 1.f / fmaxf(sqrtf(ssv), 1e-12f);
    }
    const float* A = stateBase(ws, b, m);
    const float cW2 = scl[sidx(b, m, 2)], cb2 = scl[sidx(b, m, 3)];
    const float* b2 = stateBase(ws, b, m) + (long)Dd * Dd + (long)Dd * DOUTS[m] + 1024;
    if (useK) {
      core16(sm, [&](int c, int k) { return X[(long)c * Dd + k] * sm[12544 + c]; }, A, tile * 128,
             [&](int c, int n, float v) { Y[(long)c * Dd + n] = fmaf(cW2, v, cb2 * b2[n]); });
    } else {
      core16(sm, [&](int c, int k) { return X[(long)c * Dd + k]; }, A, tile * 128,
             [&](int c, int n, float v) { Y[(long)c * Dd + n] = fmaf(cW2, v, cb2 * b2[n]); });
    }
  } else {
    if (tid < 16) {
      const float ssv = ws[OFF_RSSQ + (long)b * 2 * Cc + 16 + tid];
      sm[12544 + tid] = 1.f / fmaxf(sqrtf(ssv), 1e-12f);
    }
    const float* X = ws + OFF_KVQ + ((long)b * 3 + 2) * Cc * Dd;
    float* Y = ws + OFF_PREO + (long)b * Cc * Dd;
    const float* A = stateBase(ws, b, 5);
    const float cW2 = scl[sidx(b, 5, 2)], cb2 = scl[sidx(b, 5, 3)];
    const float* b2 = stateBase(ws, b, 5) + (long)Dd * Dd + (long)Dd * DOUTS[5] + 1024;
    core16(sm, [&](int c, int k) { return X[(long)c * Dd + k] * sm[12544 + c]; }, A, tile * 128,
           [&](int c, int n, float v) { Y[(long)c * Dd + n] = fmaf(cW2, v, cb2 * b2[n]); });
  }
}

// S4: big modules: v_hat & pred share one W1T pass -> error; memory output o -> z chunk; eta/alpha errors.
__global__ __launch_bounds__(256) void k_s4(float* ws, int t) {
  __shared__ float sm[12816 + 16];
  const int tid = threadIdx.x, bid = blockIdx.x;
  const float* scl = ws + OFF_SCALE;
  if (bid < 128) {
    const int tile = bid & 7, mi = (bid >> 3) & 3, b = bid >> 5;
    const int m = BIGM[mi];
    if (tid < 16) {
      const float ssv = ws[OFF_RSSQ + (long)b * 2 * Cc + tid];
      sm[12800 + tid] = 1.f / fmaxf(sqrtf(ssv), 1e-12f);
    }
    const float* prev = ws + OFF_PREV + ((long)b * 6 + m) * Cc * Dd;
    const float* prek = ws + OFF_PREK + ((long)b * 6 + m) * Cc * Dd;
    const float* A = stateBase(ws, b, m) + (long)Dd * Dd;
    const float cW1 = scl[sidx(b, m, 0)], cb1 = scl[sidx(b, m, 1)];
    const float* b1 = stateBase(ws, b, m) + (long)Dd * Dd + (long)Dd * DOUTS[m];
    const float* vraw = ws + OFF_KVQ + ((long)b * 3 + 1) * Cc * Dd;
    const float* kraw = ws + OFF_KVQ + ((long)b * 3 + 0) * Cc * Dd;
    float* errP = ws + OFF_ERR + ((long)b * 6 + m) * Cc * Dd;
    core16d(sm,
            [&](int c, int k) { return silu(prev[(long)c * Dd + k]); },
            [&](int c, int k) { return silu(prek[(long)c * Dd + k]); },
            A, tile * 128,
            [&](int c, int n, float v1, float v2) {
              const float vh = fmaf(cW1, v1, fmaf(cb1, b1[n], vraw[(long)c * Dd + n]));
              const float pr = fmaf(cW1, v2, fmaf(cb1, b1[n], kraw[(long)c * Dd + n] * sm[12800 + c]));
              errP[(long)c * Dd + n] = (pr - vh) * 0.0625f;
            });
  } else if (bid < 160) {
    const int id = bid - 128, tile = id & 7, b = id >> 3;
    if (tid < 16) {
      const float ssv = ws[OFF_RSSQ + (long)b * 2 * Cc + 16 + tid];
      sm[12800 + tid] = 1.f / fmaxf(sqrtf(ssv), 1e-12f);
    }
    const float* preo = ws + OFF_PREO + (long)b * Cc * Dd;
    const float* A = stateBase(ws, b, 5) + (long)Dd * Dd;
    const float cW1 = scl[sidx(b, 5, 0)], cb1 = scl[sidx(b, 5, 1)];
    const float* b1 = stateBase(ws, b, 5) + (long)Dd * Dd + (long)Dd * DOUTS[5];
    const float* qraw = ws + OFF_KVQ + ((long)b * 3 + 2) * Cc * Dd;
    float* zc = ws + OFF_Z + ((long)b * Tt + (long)t * Cc) * Dd;
    core16(sm, [&](int c, int k) { return silu(preo[(long)c * Dd + k]); }, A, tile * 128,
           [&](int c, int n, float v) {
             zc[(long)c * Dd + n] = fmaf(cW1, v, fmaf(cb1, b1[n], qraw[(long)c * Dd + n] * sm[12800 + c]));
           });
  } else {
    const int id = bid - 160, b = id >> 1, m = 3 + (id & 1);
    const float* prev = ws + OFF_PREV + ((long)b * 6 + m) * Cc * Dd;
    const float* prek = ws + OFF_PREK + ((long)b * 6 + m) * Cc * Dd;
    const float* w1 = stateBase(ws, b, m) + (long)Dd * Dd;
    float av[16], ap[16];
#pragma unroll
    for (int c = 0; c < 16; c++) { av[c] = 0.f; ap[c] = 0.f; }
    for (int jj = 0; jj < 4; jj++) {
      const int h = tid + 256 * jj;
      const float w = w1[h];
#pragma unroll
      for (int c = 0; c < 16; c++) {
        av[c] = fmaf(silu(prev[(long)c * Dd + h]), w, av[c]);
        ap[c] = fmaf(silu(prek[(long)c * Dd + h]), w, ap[c]);
      }
    }
#pragma unroll
    for (int st = 1; st < 64; st <<= 1)
#pragma unroll
      for (int c = 0; c < 16; c++) {
        av[c] += __shfl_xor(av[c], st);
        ap[c] += __shfl_xor(ap[c], st);
      }
    if ((tid & 63) == 0) {
      const int w4 = tid >> 6;
#pragma unroll
      for (int c = 0; c < 16; c++) { sm[w4 * 32 + c] = av[c]; sm[w4 * 32 + 16 + c] = ap[c]; }
    }
    __syncthreads();
    if (tid == 0) {
      const float cW1 = scl[sidx(b, m, 0)], cb1 = scl[sidx(b, m, 1)];
      const float b10 = (stateBase(ws, b, m) + (long)Dd * Dd + 1024)[0];
      float* errP = ws + OFF_ERR + ((long)b * 6 + m) * Cc * Dd;
      for (int c = 0; c < 16; c++) {
        const float sv = sm[c] + sm[32 + c] + sm[64 + c] + sm[96 + c];
        const float sp = sm[16 + c] + sm[48 + c] + sm[80 + c] + sm[112 + c];
        const float vh = fmaf(cW1, sv, cb1 * b10);
        const float pr = fmaf(cW1, sp, cb1 * b10);
        errP[(long)c * Dd] = (pr - vh) * 0.0625f;
      }
    }
  }
}

// S5: dl_dpre = (cW1 * err @ W1T_rows) * silu_grad(pre_k). Big modules via wave-reduce; eta/alpha elementwise.
__global__ __launch_bounds__(256) void k_s5(float* ws) {
  __shared__ float errl[16384];
  const int tid = threadIdx.x, bid = blockIdx.x;
  const float* scl = ws + OFF_SCALE;
  if (bid < 256) {
    const int htile = bid & 15, mi = (bid >> 4) & 3, b = bid >> 6;
    const int m = BIGM[mi];
    const float* errP = ws + OFF_ERR + ((long)b * 6 + m) * Cc * Dd;
    for (int f = tid; f < 16384; f += 256) errl[f] = errP[f];
    __syncthreads();
    const int w = tid >> 6, l = tid & 63;
    const float cW1 = scl[sidx(b, m, 0)];
    const float* A = stateBase(ws, b, m) + (long)Dd * Dd;
    const float* prek = ws + OFF_PREK + ((long)b * 6 + m) * Cc * Dd;
    float* dlp = ws + OFF_DLP + ((long)b * 6 + m) * Cc * Dd;
    const int hb = htile * 64 + w * 16;
    const int myc = l & 15, myr = l >> 4;
#pragma unroll 1
    for (int rg = 0; rg < 4; rg++) {
      const int h0 = hb + rg * 4;
      float acc[16][4];
#pragma unroll
      for (int c = 0; c < 16; c++)
#pragma unroll
        for (int r = 0; r < 4; r++) acc[c][r] = 0.f;
      const float* A0 = A + (long)h0 * Dd + l;
#pragma unroll 1
      for (int j = 0; j < 16; j++) {
        const int k = 64 * j;
        const float a0 = A0[k], a1 = A0[k + Dd], a2 = A0[k + 2 * Dd], a3 = A0[k + 3 * Dd];
        const float* ep = errl + (k + l);
#pragma unroll
        for (int c = 0; c < 16; c++) {
          const float e = ep[c * 1024];
          acc[c][0] = fmaf(e, a0, acc[c][0]);
          acc[c][1] = fmaf(e, a1, acc[c][1]);
          acc[c][2] = fmaf(e, a2, acc[c][2]);
          acc[c][3] = fmaf(e, a3, acc[c][3]);
        }
      }
#pragma unroll
      for (int st = 1; st < 64; st <<= 1)
#pragma unroll
        for (int c = 0; c < 16; c++)
#pragma unroll
          for (int r = 0; r < 4; r++) acc[c][r] += __shfl_xor(acc[c][r], st);
      float val = 0.f;
#pragma unroll
      for (int c = 0; c < 16; c++)
#pragma unroll
        for (int r = 0; r < 4; r++) val = (c == myc && r == myr) ? acc[c][r] : val;
      const int h = h0 + myr;
      const float pre = prek[(long)myc * Dd + h];
      const float sg = sigm(pre);
      const float sgrad = sg * (1.f + pre * (1.f - sg));
      dlp[(long)myc * Dd + h] = cW1 * val * sgrad;
    }
  } else {
    const int e = bid - 256, sub = e & 3, bm = e >> 2, b = bm >> 1, m = 3 + (bm & 1);
    const float cW1 = scl[sidx(b, m, 0)];
    const float* errP = ws + OFF_ERR + ((long)b * 6 + m) * Cc * Dd;
    const float* prek = ws + OFF_PREK + ((long)b * 6 + m) * Cc * Dd;
    const float* w1 = stateBase(ws, b, m) + (long)Dd * Dd;
    float* dlp = ws + OFF_DLP + ((long)b * 6 + m) * Cc * Dd;
    for (int i = tid; i < 4096; i += 256) {
      const long idx = (long)sub * 4096 + i;
      const int c = (int)(idx >> 10), h = (int)(idx & 1023);
      const float e0 = errP[(long)c * Dd];
      const float pre = prek[idx];
      const float sg = sigm(pre);
      const float sgrad = sg * (1.f + pre * (1.f - sg));
      dlp[idx] = e0 * cW1 * w1[h] * sgrad;
    }
  }
}

// S6: fused gradient + update + sumsq for W2T (all), W1T (big), vectors (b1,b2,eta/alpha W1).
__global__ __launch_bounds__(256) void k_s6(float* ws) {
  __shared__ float sm[2568];
  const int tid = threadIdx.x, bid = blockIdx.x;
  const float* scl = ws + OFF_SCALE;
  if (bid < 768) {
    const int tl = bid & 31, bm = bid >> 5, b = bm / 6, m = bm % 6;
    const int h0 = (tl & 3) * 256, d0 = (tl >> 2) * 128;
    const float* kraw = ws + OFF_KVQ + ((long)b * 3 + 0) * Cc * Dd;
    const float* rssq = ws + OFF_RSSQ + (long)b * 2 * Cc;
    for (int f = tid; f < 2048; f += 256) {
      const int c = f >> 7, dd = f & 127;
      const float nrm = fmaxf(sqrtf(rssq[c]), 1e-12f);
      sm[dd * 20 + c] = kraw[(long)c * Dd + d0 + dd] / nrm;
    }
    const float* dlpP = ws + OFF_DLP + ((long)b * 6 + m) * Cc * Dd;
    float dl[16];
    const int h = h0 + tid;
#pragma unroll
    for (int c = 0; c < 16; c++) dl[c] = dlpP[(long)c * Dd + h];
    __syncthreads();
    const float ea = ws[OFF_EA + b], aa = ws[OFF_EA + 4 + b];
    const float ac = aa * scl[sidx(b, m, 2)];
    float* W = stateBase(ws, b, m);
    float ss = 0.f;
#pragma unroll 1
    for (int dd = 0; dd < 128; dd++) {
      const float4 q0 = *reinterpret_cast<const float4*>(&sm[dd * 20 + 0]);
      const float4 q1 = *reinterpret_cast<const float4*>(&sm[dd * 20 + 4]);
      const float4 q2 = *reinterpret_cast<const float4*>(&sm[dd * 20 + 8]);
      const float4 q3 = *reinterpret_cast<const float4*>(&sm[dd * 20 + 12]);
      float g = dl[0] * q0.x; g = fmaf(dl[1], q0.y, g); g = fmaf(dl[2], q0.z, g); g = fmaf(dl[3], q0.w, g);
      g = fmaf(dl[4], q1.x, g); g = fmaf(dl[5], q1.y, g); g = fmaf(dl[6], q1.z, g); g = fmaf(dl[7], q1.w, g);
      g = fmaf(dl[8], q2.x, g); g = fmaf(dl[9], q2.y, g); g = fmaf(dl[10], q2.z, g); g = fmaf(dl[11], q2.w, g);
      g = fmaf(dl[12], q3.x, g); g = fmaf(dl[13], q3.y, g); g = fmaf(dl[14], q3.z, g); g = fmaf(dl[15], q3.w, g);
      const size_t off = (size_t)(d0 + dd) * Dd + h;
      const float nw = fmaf(ac, W[off], -ea * g);
      W[off] = nw;
      ss = fmaf(nw, nw, ss);
    }
    sumsqReduce(ss, sm + 2560, ws + OFF_SUMSQ + sidx(b, m, 2));
  } else if (bid < 1280) {
    const int id = bid - 768, tl = id & 31, bm = id >> 5, b = bm >> 2;
    const int m = BIGM[bm & 3];
    const int o0 = (tl & 3) * 256, hh0 = (tl >> 2) * 128;
    const float* prek = ws + OFF_PREK + ((long)b * 6 + m) * Cc * Dd;
    for (int f = tid; f < 2048; f += 256) {
      const int c = f >> 7, hh = f & 127;
      sm[hh * 20 + c] = silu(prek[(long)c * Dd + hh0 + hh]);
    }
    const float* errP = ws + OFF_ERR + ((long)b * 6 + m) * Cc * Dd;
    float er[16];
    const int o = o0 + tid;
#pragma unroll
    for (int c = 0; c < 16; c++) er[c] = errP[(long)c * Dd + o];
    __syncthreads();
    const float ea = ws[OFF_EA + b], aa = ws[OFF_EA + 4 + b];
    const float ac = aa * scl[sidx(b, m, 0)];
    float* W = stateBase(ws, b, m) + (long)Dd * Dd;
    float ss = 0.f;
#pragma unroll 1
    for (int hh = 0; hh < 128; hh++) {
      const float4 q0 = *reinterpret_cast<const float4*>(&sm[hh * 20 + 0]);
      const float4 q1 = *reinterpret_cast<const float4*>(&sm[hh * 20 + 4]);
      const float4 q2 = *reinterpret_cast<const float4*>(&sm[hh * 20 + 8]);
      const float4 q3 = *reinterpret_cast<const float4*>(&sm[hh * 20 + 12]);
      float g = er[0] * q0.x; g = fmaf(er[1], q0.y, g); g = fmaf(er[2], q0.z, g); g = fmaf(er[3], q0.w, g);
      g = fmaf(er[4], q1.x, g); g = fmaf(er[5], q1.y, g); g = fmaf(er[6], q1.z, g); g = fmaf(er[7], q1.w, g);
      g = fmaf(er[8], q2.x, g); g = fmaf(er[9], q2.y, g); g = fmaf(er[10], q2.z, g); g = fmaf(er[11], q2.w, g);
      g = fmaf(er[12], q3.x, g); g = fmaf(er[13], q3.y, g); g = fmaf(er[14], q3.z, g); g = fmaf(er[15], q3.w, g);
      const size_t off = (size_t)(hh0 + hh) * Dd + o;
      const float nw = fmaf(ac, W[off], -ea * g);
      W[off] = nw;
      ss = fmaf(nw, nw, ss);
    }
    sumsqReduce(ss, sm + 2560, ws + OFF_SUMSQ + sidx(b, m, 0));
  } else {
    const int id = bid - 1280;
    float ss = 0.f;
    if (id < 48) {
      const int b = id / 12, r = id % 12, m = r >> 1, which = r & 1;
      const float ea = ws[OFF_EA + b], aa = ws[OFF_EA + 4 + b];
      float* base = stateBase(ws, b, m);
      if (which == 0) {
        const int n = DOUTS[m];
        float* b1 = base + (long)Dd * Dd + (long)Dd * DOUTS[m];
        const float* errP = ws + OFF_ERR + ((long)b * 6 + m) * Cc * Dd;
        const float ac = aa * scl[sidx(b, m, 1)];
        for (int o = tid; o < n; o += 256) {
          float gsum = 0.f;
#pragma unroll
          for (int c = 0; c < 16; c++) gsum += errP[(long)c * Dd + o];
          const float nw = fmaf(ac, b1[o], -ea * gsum);
          b1[o] = nw;
          ss = fmaf(nw, nw, ss);
        }
        sumsqReduce(ss, sm + 2560, ws + OFF_SUMSQ + sidx(b, m, 1));
      } else {
        float* b2 = base + (long)Dd * Dd + (long)Dd * DOUTS[m] + 1024;
        const float* dlpP = ws + OFF_DLP + ((long)b * 6 + m) * Cc * Dd;
        const float ac = aa * scl[sidx(b, m, 3)];
        for (int hh = tid; hh < 1024; hh += 256) {
          float gsum = 0.f;
#pragma unroll
          for (int c = 0; c < 16; c++) gsum += dlpP[(long)c * Dd + hh];
          const float nw = fmaf(ac, b2[hh], -ea * gsum);
          b2[hh] = nw;
          ss = fmaf(nw, nw, ss);
        }
        sumsqReduce(ss, sm + 2560, ws + OFF_SUMSQ + sidx(b, m, 3));
      }
    } else {
      const int e2 = id - 48, b = e2 >> 1, m = 3 + (e2 & 1);
      const float ea = ws[OFF_EA + b], aa = ws[OFF_EA + 4 + b];
      float* W = stateBase(ws, b, m) + (long)Dd * Dd;
      const float* errP = ws + OFF_ERR + ((long)b * 6 + m) * Cc * Dd;
      const float* prek = ws + OFF_PREK + ((long)b * 6 + m) * Cc * Dd;
      const float ac = aa * scl[sidx(b, m, 0)];
      for (int h = tid; h < 1024; h += 256) {
        float gsum = 0.f;
#pragma unroll
        for (int c = 0; c < 16; c++)
          gsum = fmaf(errP[(long)c * Dd], silu(prek[(long)c * Dd + h]), gsum);
        const float nw = fmaf(ac, W[h], -ea * gsum);
        W[h] = nw;
        ss = fmaf(nw, nw, ss);
      }
      sumsqReduce(ss, sm + 2560, ws + OFF_SUMSQ + sidx(b, m, 0));
    }
  }
}

// ============================ epilogue ============================

__global__ __launch_bounds__(256) void k_ln(float* ws, const float* __restrict__ g,
                                            const float* __restrict__ bb) {
  __shared__ float sm[8];
  const long row = blockIdx.x;
  float* p = ws + OFF_Z + row * Dd;
  const int tid = threadIdx.x;
  float s = 0.f, s2 = 0.f;
  for (int j = tid; j < Dd; j += 256) {
    const float v = p[j];
    s += v;
    s2 = fmaf(v, v, s2);
  }
#pragma unroll
  for (int st = 32; st >= 1; st >>= 1) { s += __shfl_xor(s, st); s2 += __shfl_xor(s2, st); }
  if ((tid & 63) == 0) { sm[tid >> 6] = s; sm[4 + (tid >> 6)] = s2; }
  __syncthreads();
  const float S = sm[0] + sm[1] + sm[2] + sm[3];
  const float S2 = sm[4] + sm[5] + sm[6] + sm[7];
  const float mu = S * (1.f / 1024.f);
  const float var = S2 * (1.f / 1024.f) - mu * mu;
  const float inv = 1.f / sqrtf(var + 1e-5f);
  for (int j = tid; j < Dd; j += 256) {
    const float v = p[j];
    p[j] = fmaf((v - mu) * inv, g[j], bb[j]);
  }
}

}  // namespace

extern "C" void kernel_launch(void* const* d_in, const int* in_sizes, int n_in,
                              void* d_out, int out_size, void* d_ws, size_t ws_size,
                              hipStream_t stream) {
  (void)in_sizes; (void)n_in; (void)out_size;
  if (ws_size < (size_t)WS_FLOATS * sizeof(float)) return;  // insufficient scratch
  float* ws = (float*)d_ws;
  InPtrs ip;
  for (int i = 0; i < 31; i++) ip.p[i] = (const float*)d_in[i];

  // prologue: init state (scales=1, sumsq=0), transposed weights, z = x@in_W^T + in_b
  k_p0<<<256, 256, 0, stream>>>(ws, ip);
  k_p1<<<3072, 256, 0, stream>>>(ws, ip);
  k_gemm_big<<<4096, 256, 0, stream>>>((const float*)d_in[0], ws + OFF_INWT,
                                       (const float*)d_in[26], ws + OFF_Z);

  for (int t = 0; t < NCc; t++) {
    if (t) k_s0<<<1, 256, 0, stream>>>(ws, t);
    k_s1<<<160, 256, 0, stream>>>(ws, t);
    k_s2<<<104, 256, 0, stream>>>(ws, t);
    k_s3<<<416, 256, 0, stream>>>(ws);
    k_s4<<<168, 256, 0, stream>>>(ws, t);
    k_s5<<<288, 256, 0, stream>>>(ws);
    k_s6<<<1336, 256, 0, stream>>>(ws);
  }

  // epilogue: layernorm in place on the collected outputs, then final projection
  k_ln<<<8192, 256, 0, stream>>>(ws, (const float*)d_in[29], (const float*)d_in[30]);
  k_gemm_big<<<4096, 256, 0, stream>>>(ws + OFF_Z, ws + OFF_OUTWT,
                                       (const float*)d_in[28], (float*)d_out);
}